// Round 2
// baseline (483.565 us; speedup 1.0000x reference)
//
#include <hip/hip_runtime.h>
#include <hip/hip_cooperative_groups.h>
#include <type_traits>
#include <utility>

// ---------------- problem constants ----------------
#define B_    8
#define NQ_   1024
#define I_    21760      // 128*128 + 64*64 + 32*32 + 16*16
#define EMB_  256
#define HID_  256
#define H_    8
#define CH_   32

typedef float  f32x4  __attribute__((ext_vector_type(4)));
typedef __bf16 bf16x8 __attribute__((ext_vector_type(8)));
typedef short  s16x8  __attribute__((ext_vector_type(8)));

// ---- MFMA shim: works whether the builtin wants v8bf16 or v8i16 ----
template <typename V, typename = void>
struct bf16_mfma_native : std::false_type {};
template <typename V>
struct bf16_mfma_native<V, std::void_t<decltype(__builtin_amdgcn_mfma_f32_16x16x32_bf16(
    std::declval<V>(), std::declval<V>(), std::declval<f32x4>(), 0, 0, 0))>>
    : std::true_type {};

template <typename V>
__device__ __forceinline__ f32x4 mfma_dispatch(V a, V b, f32x4 c) {
  if constexpr (bf16_mfma_native<V>::value) {
    return __builtin_amdgcn_mfma_f32_16x16x32_bf16(a, b, c, 0, 0, 0);
  } else {
    return __builtin_amdgcn_mfma_f32_16x16x32_bf16(
        __builtin_bit_cast(s16x8, a), __builtin_bit_cast(s16x8, b), c, 0, 0, 0);
  }
}

__device__ __forceinline__ f32x4 MFMA(s16x8 a, s16x8 b, f32x4 c) {
  return mfma_dispatch(__builtin_bit_cast(bf16x8, a), __builtin_bit_cast(bf16x8, b), c);
}

// float -> bf16 bits, round-to-nearest-even
__device__ __forceinline__ unsigned short f2bf(float f) {
  unsigned u = __float_as_uint(f);
  u += 0x7fffu + ((u >> 16) & 1u);
  return (unsigned short)(u >> 16);
}

// ---------------------------------------------------------------
// GEMM phase, K fixed = 256:  Out[M,N] = A[M,256] @ W[256,N] + bias
// 512 threads = 8 waves. Wave w owns columns {s*128 + w*16 .. +15}.
// W strip in registers. A tile (32 x 256) staged fp32->bf16 in LDS
// (row stride 264). Register prefetch of the next A tile issued right
// after the barrier so HBM latency hides under the MFMAs.
// OUTM: 0 = fp32 linear [M][N], 1 = bf16 head-major [(b*8+h)][i][32]
// ---------------------------------------------------------------
template <int NS, int OUTM>
__device__ __forceinline__ void gemm_phase(
    const float* __restrict__ A, const float* __restrict__ W,
    const float* __restrict__ bias, void* __restrict__ Out,
    const int N, const int Mtiles, short* __restrict__ lds) {
  const int tid  = threadIdx.x;
  const int lane = tid & 63;
  const int wave = tid >> 6;
  const int quad = lane >> 4;
  const int ln   = lane & 15;

  // --- load W fragments (one-time, strided; L2-resident) ---
  s16x8 bfrag[NS][8];
  float bv[NS];
#pragma unroll
  for (int st = 0; st < NS; ++st) {
    const int ng = st * 128 + wave * 16 + ln;
    bv[st] = bias[ng];
#pragma unroll
    for (int ks = 0; ks < 8; ++ks) {
      s16x8 f;
#pragma unroll
      for (int j = 0; j < 8; ++j)
        f[j] = (short)f2bf(W[(ks * 32 + quad * 8 + j) * N + ng]);
      bfrag[st][ks] = f;
    }
  }

  const int sr = tid >> 4;          // staging row 0..31
  const int sc = (tid & 15) * 16;   // staging col (16 floats per thread)

  int t = blockIdx.x;
  float4 v0, v1, v2, v3;
  if (t < Mtiles) {
    const float4* src = (const float4*)(A + ((size_t)t * 32 + sr) * 256 + sc);
    v0 = src[0]; v1 = src[1]; v2 = src[2]; v3 = src[3];
  }

  for (; t < Mtiles; t += gridDim.x) {
    // --- pack the prefetched tile fp32 -> bf16 into LDS ---
    {
      s16x8 p0, p1;
      p0[0] = (short)f2bf(v0.x); p0[1] = (short)f2bf(v0.y);
      p0[2] = (short)f2bf(v0.z); p0[3] = (short)f2bf(v0.w);
      p0[4] = (short)f2bf(v1.x); p0[5] = (short)f2bf(v1.y);
      p0[6] = (short)f2bf(v1.z); p0[7] = (short)f2bf(v1.w);
      p1[0] = (short)f2bf(v2.x); p1[1] = (short)f2bf(v2.y);
      p1[2] = (short)f2bf(v2.z); p1[3] = (short)f2bf(v2.w);
      p1[4] = (short)f2bf(v3.x); p1[5] = (short)f2bf(v3.y);
      p1[6] = (short)f2bf(v3.z); p1[7] = (short)f2bf(v3.w);
      *(s16x8*)&lds[sr * 264 + sc]     = p0;
      *(s16x8*)&lds[sr * 264 + sc + 8] = p1;
    }
    __syncthreads();

    // --- issue next tile's loads NOW; they complete under the MFMAs ---
    {
      const int tn = t + gridDim.x;
      if (tn < Mtiles) {
        const float4* src = (const float4*)(A + ((size_t)tn * 32 + sr) * 256 + sc);
        v0 = src[0]; v1 = src[1]; v2 = src[2]; v3 = src[3];
      }
    }

    f32x4 acc[NS][2];
#pragma unroll
    for (int st = 0; st < NS; ++st) {
      acc[st][0] = f32x4{bv[st], bv[st], bv[st], bv[st]};
      acc[st][1] = acc[st][0];
    }
#pragma unroll
    for (int ks = 0; ks < 8; ++ks) {
      s16x8 a0 = *(const s16x8*)&lds[ln * 264 + ks * 32 + quad * 8];
      s16x8 a1 = *(const s16x8*)&lds[(ln + 16) * 264 + ks * 32 + quad * 8];
#pragma unroll
      for (int st = 0; st < NS; ++st) {
        acc[st][0] = MFMA(a0, bfrag[st][ks], acc[st][0]);
        acc[st][1] = MFMA(a1, bfrag[st][ks], acc[st][1]);
      }
    }
    // --- epilogue: D[m = quad*4+reg][n = ln] ---
    const size_t rowBase = (size_t)t * 32;
    if constexpr (OUTM == 1) {
      // bf16 head-major: [(b*8 + h)][i][32]; tiles never cross b (I_%32==0)
      const int tb  = (int)(rowBase / I_);
      const int ir0 = (int)(rowBase - (size_t)tb * I_);
      unsigned short* O = (unsigned short*)Out;
#pragma unroll
      for (int st = 0; st < NS; ++st) {
        const int ng = st * 128 + wave * 16 + ln;
        const int hh = ng >> 5, cc = ng & 31;
        const size_t pl = (size_t)(tb * 8 + hh) * I_;
#pragma unroll
        for (int rt = 0; rt < 2; ++rt) {
#pragma unroll
          for (int r = 0; r < 4; ++r) {
            const size_t i = pl + (size_t)(ir0 + rt * 16 + quad * 4 + r);
            O[i * 32 + cc] = f2bf(acc[st][rt][r]);
          }
        }
      }
    } else {
      float* O = (float*)Out;
#pragma unroll
      for (int st = 0; st < NS; ++st) {
        const int ng = st * 128 + wave * 16 + ln;
#pragma unroll
        for (int rt = 0; rt < 2; ++rt) {
#pragma unroll
          for (int r = 0; r < 4; ++r) {
            const size_t m = rowBase + rt * 16 + quad * 4 + r;
            O[m * N + ng] = acc[st][rt][r];
          }
        }
      }
    }
    __syncthreads();
  }
}

// ---------------------------------------------------------------
// Fused softmax + sampling-point + MSDA bilinear gather phase.
// 512 threads = 4 query-units of 128 threads; 8 iterations -> 32
// queries per block; 256 blocks cover all 8192 (b,n).
// Batch-per-XCD: round-robin block->XCD means bk&7 selects the XCD,
// so batch = bk&7 keeps each XCD's L2 on one batch's 11 MB.
// Phase A: thread (h,lp) does the 16-wide softmax via shfl_xor,
//   folds the 4 bilinear corners into 2 contiguous x-PAIRS
//   (head-major imgp: pair = 128 contiguous bytes) -> LDS.
// Phase B: thread (h,c2): p=c2>>3 picks pair element, 8 threads
//   cover a 64B pixel slice with uint2 loads; shfl_xor(8) combines
//   the two pair halves; each thread stores float2.
// ---------------------------------------------------------------
__device__ __forceinline__ void msda_phase(
    const unsigned int* __restrict__ imgp,  // bf16 pairs, head-major [(b*8+h)*I_][16] uints
    const float* __restrict__ qp, const float* __restrict__ refp,
    float* __restrict__ out, char* __restrict__ smem) {
  float (*sw)[4]  = (float(*)[4])smem;          // [512][4] floats = 8 KB
  int   (*sib)[2] = (int(*)[2])(smem + 8192);   // [512][2] ints   = 4 KB
  const int tid = threadIdx.x;
  const int u = tid >> 7, t = tid & 127;
  const int bk = blockIdx.x;

  for (int it = 0; it < 8; ++it) {
    const int bid = ((bk & 7) << 10) | ((bk >> 3) << 5) | (it << 2) | u;
    const int b   = bid >> 10;
    {
      const int h = t >> 4, lp = t & 15, l = lp >> 2;
      const int ww = 128 >> l;                              // square levels
      const int start = (65536 - (65536 >> (2 * l))) / 3;   // 0,16384,20480,21504
      const float invsh = __uint_as_float((unsigned)(120 + l) << 23);  // 1/ww exactly

      const float* qb = qp + (size_t)bid * 384 + h * 48 + lp * 3;
      const float ox = qb[0], oy = qb[1], z = qb[2];
      // softmax over the 16 lanes of this (q,h) group
      float m = z;
      m = fmaxf(m, __shfl_xor(m, 1, 16));
      m = fmaxf(m, __shfl_xor(m, 2, 16));
      m = fmaxf(m, __shfl_xor(m, 4, 16));
      m = fmaxf(m, __shfl_xor(m, 8, 16));
      float e = __expf(z - m);
      float s = e;
      s += __shfl_xor(s, 1, 16);
      s += __shfl_xor(s, 2, 16);
      s += __shfl_xor(s, 4, 16);
      s += __shfl_xor(s, 8, 16);
      const float a = e / s;

      const float rx = refp[bid * 2], ry = refp[bid * 2 + 1];
      const float x = (rx + ox * invsh) * (float)ww - 0.5f;
      const float y = (ry + oy * invsh) * (float)ww - 0.5f;
      const float x0f = floorf(x), y0f = floorf(y);
      const float wx = x - x0f, wy = y - y0f;
      const int x0 = (int)x0f, y0 = (int)y0f;

      // fold x-corners onto the contiguous pair (xb, xb+1)
      const int xb = min(max(x0, 0), ww - 2);
      float u0 = 0.f, u1 = 0.f;
      if (x0 >= 0 && x0 < ww)         { if (x0 == xb)     u0 += 1.f - wx; else u1 += 1.f - wx; }
      if (x0 + 1 >= 0 && x0 + 1 < ww) { if (x0 + 1 == xb) u0 += wx;       else u1 += wx; }
      const float wy0 = (y0 >= 0     && y0 < ww)     ? a * (1.f - wy) : 0.f;
      const float wy1 = (y0 + 1 >= 0 && y0 + 1 < ww) ? a * wy         : 0.f;
      const int yc0 = min(max(y0, 0), ww - 1);
      const int yc1 = min(max(y0 + 1, 0), ww - 1);

      const int pb = (b * 8 + h) * I_ + start + xb;
      sw[tid][0] = wy0 * u0; sw[tid][1] = wy0 * u1;
      sw[tid][2] = wy1 * u0; sw[tid][3] = wy1 * u1;
      sib[tid][0] = (pb + yc0 * ww) * 16;   // uint (bf16-pair) units
      sib[tid][1] = (pb + yc1 * ww) * 16;
    }
    __syncthreads();

    {
      const int h = t >> 4, c2 = t & 15;
      const int p  = c2 >> 3;                    // which pixel of the x-pair
      const int cp = ((c2 & 7) << 1) + (p << 4); // uint offset: pair element + channel pair
      float a0 = 0.f, a1 = 0.f, a2 = 0.f, a3 = 0.f;
#pragma unroll
      for (int lp = 0; lp < 16; ++lp) {
        const float4 w4 = *(const float4*)sw[(u << 7) + h * 16 + lp];  // LDS broadcast
        const int2   ib = *(const int2*)sib[(u << 7) + h * 16 + lp];
        const float w0 = p ? w4.y : w4.x;   // row y0 weight for my pixel
        const float w1 = p ? w4.w : w4.z;   // row y1 weight for my pixel
        const uint2 ua = *(const uint2*)&imgp[ib.x + cp];
        const uint2 ub = *(const uint2*)&imgp[ib.y + cp];
        a0 += w0 * __uint_as_float(ua.x << 16);
        a1 += w0 * __uint_as_float(ua.x & 0xffff0000u);
        a2 += w0 * __uint_as_float(ua.y << 16);
        a3 += w0 * __uint_as_float(ua.y & 0xffff0000u);
        a0 += w1 * __uint_as_float(ub.x << 16);
        a1 += w1 * __uint_as_float(ub.x & 0xffff0000u);
        a2 += w1 * __uint_as_float(ub.y << 16);
        a3 += w1 * __uint_as_float(ub.y & 0xffff0000u);
      }
      // combine the two halves of the x-pair (lanes c2 and c2^8, same h)
      a0 += __shfl_xor(a0, 8);
      a1 += __shfl_xor(a1, 8);
      a2 += __shfl_xor(a2, 8);
      a3 += __shfl_xor(a3, 8);
      float2 r;
      r.x = p ? a2 : a0;
      r.y = p ? a3 : a1;
      *(float2*)&out[(size_t)bid * 256 + h * 32 + ((c2 & 7) << 2) + (p << 1)] = r;
    }
    __syncthreads();
  }
}

// ---------------------------------------------------------------
// Cooperative mega-kernel: all four stages, two grid-wide syncs.
// 256 blocks x 512 threads -> 1 block/CU, guaranteed co-resident.
// ---------------------------------------------------------------
__global__ __launch_bounds__(512, 2) void mega_kernel(
    const float* __restrict__ img, const float* __restrict__ queries,
    const float* __restrict__ refp, const float* __restrict__ W_img,
    const float* __restrict__ b_img, const float* __restrict__ W_q,
    const float* __restrict__ b_q, const float* __restrict__ W_out,
    const float* __restrict__ b_out, unsigned short* __restrict__ imgp,
    float* __restrict__ qp, float* __restrict__ msda,
    float* __restrict__ out) {
  __shared__ __align__(16) char smem[32 * 264 * 2];  // 16896 B, shared by all phases

  // Phase 1a: img_p = img @ W_img + b_img  (174080x256 -> bf16 head-major)
  gemm_phase<2, 1>(img, W_img, b_img, (void*)imgp, 256, (B_ * I_) / 32, (short*)smem);
  // Phase 1b (independent): qp = queries @ W_q + b_q  (8192x384 fp32)
  gemm_phase<3, 0>(queries, W_q, b_q, (void*)qp, 384, (B_ * NQ_) / 32, (short*)smem);

  __threadfence();
  cooperative_groups::this_grid().sync();

  // Phase 2: fused softmax + sampling + bilinear gather
  msda_phase((const unsigned int*)imgp, qp, refp, msda, smem);

  __threadfence();
  cooperative_groups::this_grid().sync();

  // Phase 3: out = msda @ W_out + b_out  (8192x256 fp32)
  gemm_phase<2, 0>(msda, W_out, b_out, (void*)out, 256, (B_ * NQ_) / 32, (short*)smem);
}

// ---------------------------------------------------------------
// Standalone wrappers (fallback path if cooperative launch fails)
// ---------------------------------------------------------------
template <int NS, int OUTM>
__global__ __launch_bounds__(512) void gemm_k256(
    const float* __restrict__ A, const float* __restrict__ W,
    const float* __restrict__ bias, void* __restrict__ Out,
    const int N, const int Mtiles) {
  __shared__ __align__(16) short lds[32 * 264];
  gemm_phase<NS, OUTM>(A, W, bias, Out, N, Mtiles, lds);
}

__global__ __launch_bounds__(512) void msda_standalone(
    const unsigned int* __restrict__ imgp, const float* __restrict__ qp,
    const float* __restrict__ refp, float* __restrict__ out) {
  __shared__ __align__(16) char smem[12288];
  msda_phase(imgp, qp, refp, out, smem);
}

// ---------------------------------------------------------------
// workspace layout (bytes)
// ---------------------------------------------------------------
#define OFF_IMGP 0ULL                        // 8*8*21760*32*2 = 89,128,960 (bf16, head-major)
#define OFF_QP   89128960ULL                 // 8192*384*4     = 12,582,912
#define OFF_MSDA 101711872ULL                // 8192*256*4     =  8,388,608
#define WS_NEEDED 110100480ULL

extern "C" void kernel_launch(void* const* d_in, const int* in_sizes, int n_in,
                              void* d_out, int out_size, void* d_ws, size_t ws_size,
                              hipStream_t stream) {
  const float* img     = (const float*)d_in[0];
  const float* queries = (const float*)d_in[2];
  const float* refp    = (const float*)d_in[3];
  const float* W_img   = (const float*)d_in[4];
  const float* b_img   = (const float*)d_in[5];
  const float* W_q     = (const float*)d_in[6];
  const float* b_q     = (const float*)d_in[7];
  const float* W_out   = (const float*)d_in[8];
  const float* b_out   = (const float*)d_in[9];

  if (ws_size < WS_NEEDED) return;  // workspace too small -> fail loudly

  char* ws = (char*)d_ws;
  unsigned short* imgp = (unsigned short*)(ws + OFF_IMGP);
  float* qp   = (float*)(ws + OFF_QP);
  float* msda = (float*)(ws + OFF_MSDA);
  float* outf = (float*)d_out;

  void* args[13] = {(void*)&img,  (void*)&queries, (void*)&refp,
                    (void*)&W_img, (void*)&b_img,  (void*)&W_q,   (void*)&b_q,
                    (void*)&W_out, (void*)&b_out,  (void*)&imgp,
                    (void*)&qp,    (void*)&msda,   (void*)&outf};
  hipError_t err = hipLaunchCooperativeKernel(
      reinterpret_cast<void*>(mega_kernel), dim3(256), dim3(512), args, 0, stream);

  if (err != hipSuccess) {
    (void)hipGetLastError();  // clear sticky error, fall back to 4-launch path
    hipLaunchKernelGGL((gemm_k256<2, 1>), dim3(512), dim3(512), 0, stream,
                       img, W_img, b_img, (void*)imgp, 256, I_ * B_ / 32);
    hipLaunchKernelGGL((gemm_k256<3, 0>), dim3(256), dim3(512), 0, stream,
                       queries, W_q, b_q, (void*)qp, 384, B_ * NQ_ / 32);
    hipLaunchKernelGGL(msda_standalone, dim3(256), dim3(512), 0, stream,
                       (const unsigned int*)imgp, qp, refp, msda);
    hipLaunchKernelGGL((gemm_k256<2, 0>), dim3(256), dim3(512), 0, stream,
                       msda, W_out, b_out, (void*)outf, 256, B_ * NQ_ / 32);
  }
}

// Round 3
// 338.176 us; speedup vs baseline: 1.4299x; 1.4299x over previous
//
#include <hip/hip_runtime.h>
#include <type_traits>
#include <utility>

// ---------------- problem constants ----------------
#define B_    8
#define NQ_   1024
#define I_    21760      // 128*128 + 64*64 + 32*32 + 16*16
#define EMB_  256
#define HID_  256
#define H_    8
#define CH_   32

typedef float  f32x4  __attribute__((ext_vector_type(4)));
typedef __bf16 bf16x8 __attribute__((ext_vector_type(8)));
typedef short  s16x8  __attribute__((ext_vector_type(8)));

// ---- MFMA shim: works whether the builtin wants v8bf16 or v8i16 ----
template <typename V, typename = void>
struct bf16_mfma_native : std::false_type {};
template <typename V>
struct bf16_mfma_native<V, std::void_t<decltype(__builtin_amdgcn_mfma_f32_16x16x32_bf16(
    std::declval<V>(), std::declval<V>(), std::declval<f32x4>(), 0, 0, 0))>>
    : std::true_type {};

template <typename V>
__device__ __forceinline__ f32x4 mfma_dispatch(V a, V b, f32x4 c) {
  if constexpr (bf16_mfma_native<V>::value) {
    return __builtin_amdgcn_mfma_f32_16x16x32_bf16(a, b, c, 0, 0, 0);
  } else {
    return __builtin_amdgcn_mfma_f32_16x16x32_bf16(
        __builtin_bit_cast(s16x8, a), __builtin_bit_cast(s16x8, b), c, 0, 0, 0);
  }
}

__device__ __forceinline__ f32x4 MFMA(s16x8 a, s16x8 b, f32x4 c) {
  return mfma_dispatch(__builtin_bit_cast(bf16x8, a), __builtin_bit_cast(bf16x8, b), c);
}

// float -> bf16 bits, round-to-nearest-even
__device__ __forceinline__ unsigned short f2bf(float f) {
  unsigned u = __float_as_uint(f);
  u += 0x7fffu + ((u >> 16) & 1u);
  return (unsigned short)(u >> 16);
}

// ---------------------------------------------------------------
// Generic GEMM, K fixed = 256:  Out[M,N] = A[M,256] @ W[256,N] + bias
// 512 threads = 8 waves. Wave w owns columns {s*128 + w*16 .. +15}.
// W strip in registers. A tile (32 x 256) staged fp32->bf16 in LDS
// (row stride 264). Register prefetch of the next A tile is issued
// right after the barrier so HBM latency hides under the MFMAs.
// OUTM: 0 = fp32 linear [M][N], 1 = bf16 head-major [(b*8+h)][i][32]
// ---------------------------------------------------------------
template <int NS, int OUTM>
__global__ __launch_bounds__(512) void gemm_k256(
    const float* __restrict__ A, const float* __restrict__ W,
    const float* __restrict__ bias, void* __restrict__ Out,
    const int N, const int Mtiles) {
  __shared__ __align__(16) short lds[32 * 264];
  const int tid  = threadIdx.x;
  const int lane = tid & 63;
  const int wave = tid >> 6;
  const int quad = lane >> 4;
  const int ln   = lane & 15;

  // --- load W fragments (one-time, strided; L2-resident) ---
  s16x8 bfrag[NS][8];
  float bv[NS];
#pragma unroll
  for (int st = 0; st < NS; ++st) {
    const int ng = st * 128 + wave * 16 + ln;
    bv[st] = bias[ng];
#pragma unroll
    for (int ks = 0; ks < 8; ++ks) {
      s16x8 f;
#pragma unroll
      for (int j = 0; j < 8; ++j)
        f[j] = (short)f2bf(W[(ks * 32 + quad * 8 + j) * N + ng]);
      bfrag[st][ks] = f;
    }
  }

  const int sr = tid >> 4;          // staging row 0..31
  const int sc = (tid & 15) * 16;   // staging col (16 floats per thread)

  int t = blockIdx.x;
  float4 v0, v1, v2, v3;
  if (t < Mtiles) {
    const float4* src = (const float4*)(A + ((size_t)t * 32 + sr) * 256 + sc);
    v0 = src[0]; v1 = src[1]; v2 = src[2]; v3 = src[3];
  }

  for (; t < Mtiles; t += gridDim.x) {
    // --- pack the prefetched tile fp32 -> bf16 into LDS ---
    {
      s16x8 p0, p1;
      p0[0] = (short)f2bf(v0.x); p0[1] = (short)f2bf(v0.y);
      p0[2] = (short)f2bf(v0.z); p0[3] = (short)f2bf(v0.w);
      p0[4] = (short)f2bf(v1.x); p0[5] = (short)f2bf(v1.y);
      p0[6] = (short)f2bf(v1.z); p0[7] = (short)f2bf(v1.w);
      p1[0] = (short)f2bf(v2.x); p1[1] = (short)f2bf(v2.y);
      p1[2] = (short)f2bf(v2.z); p1[3] = (short)f2bf(v2.w);
      p1[4] = (short)f2bf(v3.x); p1[5] = (short)f2bf(v3.y);
      p1[6] = (short)f2bf(v3.z); p1[7] = (short)f2bf(v3.w);
      *(s16x8*)&lds[sr * 264 + sc]     = p0;
      *(s16x8*)&lds[sr * 264 + sc + 8] = p1;
    }
    __syncthreads();

    // --- issue next tile's loads NOW; they complete under the MFMAs ---
    {
      const int tn = t + gridDim.x;
      if (tn < Mtiles) {
        const float4* src = (const float4*)(A + ((size_t)tn * 32 + sr) * 256 + sc);
        v0 = src[0]; v1 = src[1]; v2 = src[2]; v3 = src[3];
      }
    }

    f32x4 acc[NS][2];
#pragma unroll
    for (int st = 0; st < NS; ++st) {
      acc[st][0] = f32x4{bv[st], bv[st], bv[st], bv[st]};
      acc[st][1] = acc[st][0];
    }
#pragma unroll
    for (int ks = 0; ks < 8; ++ks) {
      s16x8 a0 = *(const s16x8*)&lds[ln * 264 + ks * 32 + quad * 8];
      s16x8 a1 = *(const s16x8*)&lds[(ln + 16) * 264 + ks * 32 + quad * 8];
#pragma unroll
      for (int st = 0; st < NS; ++st) {
        acc[st][0] = MFMA(a0, bfrag[st][ks], acc[st][0]);
        acc[st][1] = MFMA(a1, bfrag[st][ks], acc[st][1]);
      }
    }
    // --- epilogue: D[m = quad*4+reg][n = ln] ---
    const size_t rowBase = (size_t)t * 32;
    if constexpr (OUTM == 1) {
      // bf16 head-major: [(b*8 + h)][i][32]; tiles never cross b (I_%32==0)
      const int tb  = (int)(rowBase / I_);
      const int ir0 = (int)(rowBase - (size_t)tb * I_);
      unsigned short* O = (unsigned short*)Out;
#pragma unroll
      for (int st = 0; st < NS; ++st) {
        const int ng = st * 128 + wave * 16 + ln;
        const int hh = ng >> 5, cc = ng & 31;
        const size_t pl = (size_t)(tb * 8 + hh) * I_;
#pragma unroll
        for (int rt = 0; rt < 2; ++rt) {
#pragma unroll
          for (int r = 0; r < 4; ++r) {
            const size_t i = pl + (size_t)(ir0 + rt * 16 + quad * 4 + r);
            O[i * 32 + cc] = f2bf(acc[st][rt][r]);
          }
        }
      }
    } else {
      float* O = (float*)Out;
#pragma unroll
      for (int st = 0; st < NS; ++st) {
        const int ng = st * 128 + wave * 16 + ln;
#pragma unroll
        for (int rt = 0; rt < 2; ++rt) {
#pragma unroll
          for (int r = 0; r < 4; ++r) {
            const size_t m = rowBase + rt * 16 + quad * 4 + r;
            O[m * N + ng] = acc[st][rt][r];
          }
        }
      }
    }
    __syncthreads();
  }
}

// ---------------------------------------------------------------
// Fused softmax + sampling-point + MSDA bilinear gather.
// Block = (batch b, head h, 8 queries); 128 threads; grid 8192.
// XCD locality: hw blocks round-robin XCDs by blk&7, so we assign
//   x = blk&7 (XCD), j = blk>>3 (sequence within XCD),
//   combo c = ((j>>7)<<3)|x  ->  b = c>>3, h = c&7, qg = j&127.
// Each XCD thus works through combos (b=0..7, h=x) in runs of 128
// consecutive blocks; the active working set per XCD is ~1-3 head
// slices of 1.36 MB each -> fits the 4 MB XCD L2 (vs 11 MB before).
// Phase A: thread (q8,lp): 16-wide softmax via shfl_xor, fold the 4
//   bilinear corners into 2 contiguous x-PAIRS (head-major imgp:
//   pair = 128 B) -> LDS weights + gather bases.
// Phase B: thread (q8,c2): p=c2>>3 picks the pair element, 8 threads
//   cover a 64 B pixel slice with uint2 loads; shfl_xor(8) combines
//   the two pair halves; each thread stores float2.
// ---------------------------------------------------------------
__global__ __launch_bounds__(128) void msda_kernel(
    const unsigned int* __restrict__ imgp,  // bf16 pairs, head-major [(b*8+h)*I_][16] uints
    const float* __restrict__ qp, const float* __restrict__ refp,
    float* __restrict__ out) {
  __shared__ __align__(16) float sw[128][4];
  __shared__ __align__(16) int   sib[128][2];
  const int blk = blockIdx.x;
  const int x   = blk & 7;            // XCD
  const int j   = blk >> 3;           // 0..1023
  const int c   = ((j >> 7) << 3) | x;  // (b,h) combo, 128 blocks per combo
  const int b   = c >> 3, h = c & 7;
  const int qg  = j & 127;            // query group -> queries qg*8 .. qg*8+7
  const int tid = threadIdx.x;
  const int pl  = (b * 8 + h) * I_;   // head-plane base (pixel units)

  {
    const int q8 = tid >> 4, lp = tid & 15, l = lp >> 2;
    const int ww = 128 >> l;                              // square levels
    const int start = (65536 - (65536 >> (2 * l))) / 3;   // 0,16384,20480,21504
    const float invsh = __uint_as_float((unsigned)(120 + l) << 23);  // 1/ww exactly

    const int n   = (qg << 3) | q8;
    const int bid = (b << 10) | n;
    const float* qb = qp + (size_t)bid * 384 + h * 48 + lp * 3;
    const float ox = qb[0], oy = qb[1], z = qb[2];
    // softmax over the 16 lanes of this (q,h) group
    float m = z;
    m = fmaxf(m, __shfl_xor(m, 1, 16));
    m = fmaxf(m, __shfl_xor(m, 2, 16));
    m = fmaxf(m, __shfl_xor(m, 4, 16));
    m = fmaxf(m, __shfl_xor(m, 8, 16));
    float e = __expf(z - m);
    float s = e;
    s += __shfl_xor(s, 1, 16);
    s += __shfl_xor(s, 2, 16);
    s += __shfl_xor(s, 4, 16);
    s += __shfl_xor(s, 8, 16);
    const float a = e / s;

    const float rx = refp[bid * 2], ry = refp[bid * 2 + 1];
    const float px = (rx + ox * invsh) * (float)ww - 0.5f;
    const float py = (ry + oy * invsh) * (float)ww - 0.5f;
    const float x0f = floorf(px), y0f = floorf(py);
    const float wx = px - x0f, wy = py - y0f;
    const int x0 = (int)x0f, y0 = (int)y0f;

    // fold x-corners onto the contiguous pair (xb, xb+1)
    const int xb = min(max(x0, 0), ww - 2);
    float u0 = 0.f, u1 = 0.f;
    if (x0 >= 0 && x0 < ww)         { if (x0 == xb)     u0 += 1.f - wx; else u1 += 1.f - wx; }
    if (x0 + 1 >= 0 && x0 + 1 < ww) { if (x0 + 1 == xb) u0 += wx;       else u1 += wx; }
    const float wy0 = (y0 >= 0     && y0 < ww)     ? a * (1.f - wy) : 0.f;
    const float wy1 = (y0 + 1 >= 0 && y0 + 1 < ww) ? a * wy         : 0.f;
    const int yc0 = min(max(y0, 0), ww - 1);
    const int yc1 = min(max(y0 + 1, 0), ww - 1);

    const int pb = pl + start + xb;
    sw[tid][0] = wy0 * u0; sw[tid][1] = wy0 * u1;
    sw[tid][2] = wy1 * u0; sw[tid][3] = wy1 * u1;
    sib[tid][0] = (pb + yc0 * ww) * 16;   // uint (bf16-pair) units
    sib[tid][1] = (pb + yc1 * ww) * 16;
  }
  __syncthreads();

  const int q8 = tid >> 4, c2 = tid & 15;
  const int p  = c2 >> 3;                    // which pixel of the x-pair
  const int cp = ((c2 & 7) << 1) + (p << 4); // uint offset: pair element + channel pair
  float a0 = 0.f, a1 = 0.f, a2 = 0.f, a3 = 0.f;
#pragma unroll
  for (int lp = 0; lp < 16; ++lp) {
    const float4 w4 = *(const float4*)sw[q8 * 16 + lp];   // LDS broadcast
    const int2   ib = *(const int2*)sib[q8 * 16 + lp];
    const float w0 = p ? w4.y : w4.x;   // row y0 weight for my pixel
    const float w1 = p ? w4.w : w4.z;   // row y1 weight for my pixel
    const uint2 ua = *(const uint2*)&imgp[ib.x + cp];
    const uint2 ub = *(const uint2*)&imgp[ib.y + cp];
    a0 += w0 * __uint_as_float(ua.x << 16);
    a1 += w0 * __uint_as_float(ua.x & 0xffff0000u);
    a2 += w0 * __uint_as_float(ua.y << 16);
    a3 += w0 * __uint_as_float(ua.y & 0xffff0000u);
    a0 += w1 * __uint_as_float(ub.x << 16);
    a1 += w1 * __uint_as_float(ub.x & 0xffff0000u);
    a2 += w1 * __uint_as_float(ub.y << 16);
    a3 += w1 * __uint_as_float(ub.y & 0xffff0000u);
  }
  // combine the two halves of the x-pair (lanes c2 and c2^8, same q8)
  a0 += __shfl_xor(a0, 8);
  a1 += __shfl_xor(a1, 8);
  a2 += __shfl_xor(a2, 8);
  a3 += __shfl_xor(a3, 8);
  float2 r;
  r.x = p ? a2 : a0;
  r.y = p ? a3 : a1;
  const int bid = (b << 10) | (qg << 3) | q8;
  *(float2*)&out[(size_t)bid * 256 + h * 32 + ((c2 & 7) << 2) + (p << 1)] = r;
}

// ---------------------------------------------------------------
// workspace layout (bytes)
// ---------------------------------------------------------------
#define OFF_IMGP 0ULL                        // 8*8*21760*32*2 = 89,128,960 (bf16, head-major)
#define OFF_QP   89128960ULL                 // 8192*384*4     = 12,582,912
#define OFF_MSDA 101711872ULL                // 8192*256*4     =  8,388,608
#define WS_NEEDED 110100480ULL

extern "C" void kernel_launch(void* const* d_in, const int* in_sizes, int n_in,
                              void* d_out, int out_size, void* d_ws, size_t ws_size,
                              hipStream_t stream) {
  const float* img     = (const float*)d_in[0];
  const float* queries = (const float*)d_in[2];
  const float* refp    = (const float*)d_in[3];
  const float* W_img   = (const float*)d_in[4];
  const float* b_img   = (const float*)d_in[5];
  const float* W_q     = (const float*)d_in[6];
  const float* b_q     = (const float*)d_in[7];
  const float* W_out   = (const float*)d_in[8];
  const float* b_out   = (const float*)d_in[9];

  if (ws_size < WS_NEEDED) return;  // workspace too small -> fail loudly

  char* ws = (char*)d_ws;
  unsigned short* imgp = (unsigned short*)(ws + OFF_IMGP);
  float* qp   = (float*)(ws + OFF_QP);
  float* msda = (float*)(ws + OFF_MSDA);

  // qp = queries @ W_q + b_q      (8192 x 384) -> fp32
  hipLaunchKernelGGL((gemm_k256<3, 0>), dim3(256), dim3(512), 0, stream,
                     queries, W_q, b_q, (void*)qp, 384, B_ * NQ_ / 32);
  // img_p = img @ W_img + b_img   (174080 x 256) -> bf16 head-major [(b,h)][i][ch]
  hipLaunchKernelGGL((gemm_k256<2, 1>), dim3(512), dim3(512), 0, stream,
                     img, W_img, b_img, (void*)imgp, 256, I_ * B_ / 32);
  // fused softmax + sampling + bilinear gather (per-head blocks)
  hipLaunchKernelGGL(msda_kernel, dim3(B_ * NQ_ * H_ / 8), dim3(128), 0, stream,
                     (const unsigned int*)imgp, qp, refp, msda);
  // out = msda @ W_out + b_out    (8192 x 256) -> fp32
  hipLaunchKernelGGL((gemm_k256<2, 0>), dim3(256), dim3(512), 0, stream,
                     msda, W_out, b_out, d_out, 256, B_ * NQ_ / 32);
}

// Round 4
// 334.424 us; speedup vs baseline: 1.4460x; 1.0112x over previous
//
#include <hip/hip_runtime.h>
#include <type_traits>
#include <utility>

// ---------------- problem constants ----------------
#define B_    8
#define NQ_   1024
#define I_    21760      // 128*128 + 64*64 + 32*32 + 16*16
#define EMB_  256
#define HID_  256
#define H_    8
#define CH_   32

typedef float  f32x4  __attribute__((ext_vector_type(4)));
typedef __bf16 bf16x8 __attribute__((ext_vector_type(8)));
typedef short  s16x8  __attribute__((ext_vector_type(8)));

// ---- MFMA shim: works whether the builtin wants v8bf16 or v8i16 ----
template <typename V, typename = void>
struct bf16_mfma_native : std::false_type {};
template <typename V>
struct bf16_mfma_native<V, std::void_t<decltype(__builtin_amdgcn_mfma_f32_16x16x32_bf16(
    std::declval<V>(), std::declval<V>(), std::declval<f32x4>(), 0, 0, 0))>>
    : std::true_type {};

template <typename V>
__device__ __forceinline__ f32x4 mfma_dispatch(V a, V b, f32x4 c) {
  if constexpr (bf16_mfma_native<V>::value) {
    return __builtin_amdgcn_mfma_f32_16x16x32_bf16(a, b, c, 0, 0, 0);
  } else {
    return __builtin_amdgcn_mfma_f32_16x16x32_bf16(
        __builtin_bit_cast(s16x8, a), __builtin_bit_cast(s16x8, b), c, 0, 0, 0);
  }
}

__device__ __forceinline__ f32x4 MFMA(s16x8 a, s16x8 b, f32x4 c) {
  return mfma_dispatch(__builtin_bit_cast(bf16x8, a), __builtin_bit_cast(bf16x8, b), c);
}

// float -> bf16 bits, round-to-nearest-even
__device__ __forceinline__ unsigned short f2bf(float f) {
  unsigned u = __float_as_uint(f);
  u += 0x7fffu + ((u >> 16) & 1u);
  return (unsigned short)(u >> 16);
}

// ---------------------------------------------------------------
// GEMM phase, K fixed = 256:  Out[M,N] = A[M,256] @ W[256,N] + bias
// 512 threads = 8 waves. Wave w owns columns {s*128 + w*16 .. +15}.
// W strip in registers. A tile (32 x 256) staged fp32->bf16 in LDS
// (row stride 264). Register prefetch of the next A tile is issued
// right after the barrier so HBM latency hides under the MFMAs.
// OUTM: 0 = fp32 linear [M][N], 1 = bf16 head-major [(b*8+h)][i][32]
// ---------------------------------------------------------------
template <int NS, int OUTM>
__device__ __forceinline__ void gemm_phase(
    const float* __restrict__ A, const float* __restrict__ W,
    const float* __restrict__ bias, void* __restrict__ Out,
    const int N, const int Mtiles, short* __restrict__ lds,
    const int bid0, const int nblk) {
  const int tid  = threadIdx.x;
  const int lane = tid & 63;
  const int wave = tid >> 6;
  const int quad = lane >> 4;
  const int ln   = lane & 15;

  // --- load W fragments (one-time, strided; L2-resident) ---
  s16x8 bfrag[NS][8];
  float bv[NS];
#pragma unroll
  for (int st = 0; st < NS; ++st) {
    const int ng = st * 128 + wave * 16 + ln;
    bv[st] = bias[ng];
#pragma unroll
    for (int ks = 0; ks < 8; ++ks) {
      s16x8 f;
#pragma unroll
      for (int j = 0; j < 8; ++j)
        f[j] = (short)f2bf(W[(ks * 32 + quad * 8 + j) * N + ng]);
      bfrag[st][ks] = f;
    }
  }

  const int sr = tid >> 4;          // staging row 0..31
  const int sc = (tid & 15) * 16;   // staging col (16 floats per thread)

  int t = bid0;
  float4 v0, v1, v2, v3;
  if (t < Mtiles) {
    const float4* src = (const float4*)(A + ((size_t)t * 32 + sr) * 256 + sc);
    v0 = src[0]; v1 = src[1]; v2 = src[2]; v3 = src[3];
  }

  for (; t < Mtiles; t += nblk) {
    // --- pack the prefetched tile fp32 -> bf16 into LDS ---
    {
      s16x8 p0, p1;
      p0[0] = (short)f2bf(v0.x); p0[1] = (short)f2bf(v0.y);
      p0[2] = (short)f2bf(v0.z); p0[3] = (short)f2bf(v0.w);
      p0[4] = (short)f2bf(v1.x); p0[5] = (short)f2bf(v1.y);
      p0[6] = (short)f2bf(v1.z); p0[7] = (short)f2bf(v1.w);
      p1[0] = (short)f2bf(v2.x); p1[1] = (short)f2bf(v2.y);
      p1[2] = (short)f2bf(v2.z); p1[3] = (short)f2bf(v2.w);
      p1[4] = (short)f2bf(v3.x); p1[5] = (short)f2bf(v3.y);
      p1[6] = (short)f2bf(v3.z); p1[7] = (short)f2bf(v3.w);
      *(s16x8*)&lds[sr * 264 + sc]     = p0;
      *(s16x8*)&lds[sr * 264 + sc + 8] = p1;
    }
    __syncthreads();

    // --- issue next tile's loads NOW; they complete under the MFMAs ---
    {
      const int tn = t + nblk;
      if (tn < Mtiles) {
        const float4* src = (const float4*)(A + ((size_t)tn * 32 + sr) * 256 + sc);
        v0 = src[0]; v1 = src[1]; v2 = src[2]; v3 = src[3];
      }
    }

    f32x4 acc[NS][2];
#pragma unroll
    for (int st = 0; st < NS; ++st) {
      acc[st][0] = f32x4{bv[st], bv[st], bv[st], bv[st]};
      acc[st][1] = acc[st][0];
    }
#pragma unroll
    for (int ks = 0; ks < 8; ++ks) {
      s16x8 a0 = *(const s16x8*)&lds[ln * 264 + ks * 32 + quad * 8];
      s16x8 a1 = *(const s16x8*)&lds[(ln + 16) * 264 + ks * 32 + quad * 8];
#pragma unroll
      for (int st = 0; st < NS; ++st) {
        acc[st][0] = MFMA(a0, bfrag[st][ks], acc[st][0]);
        acc[st][1] = MFMA(a1, bfrag[st][ks], acc[st][1]);
      }
    }
    // --- epilogue: D[m = quad*4+reg][n = ln] ---
    const size_t rowBase = (size_t)t * 32;
    if constexpr (OUTM == 1) {
      // bf16 head-major: [(b*8 + h)][i][32]; tiles never cross b (I_%32==0)
      const int tb  = (int)(rowBase / I_);
      const int ir0 = (int)(rowBase - (size_t)tb * I_);
      unsigned short* O = (unsigned short*)Out;
#pragma unroll
      for (int st = 0; st < NS; ++st) {
        const int ng = st * 128 + wave * 16 + ln;
        const int hh = ng >> 5, cc = ng & 31;
        const size_t pl = (size_t)(tb * 8 + hh) * I_;
#pragma unroll
        for (int rt = 0; rt < 2; ++rt) {
#pragma unroll
          for (int r = 0; r < 4; ++r) {
            const size_t i = pl + (size_t)(ir0 + rt * 16 + quad * 4 + r);
            O[i * 32 + cc] = f2bf(acc[st][rt][r]);
          }
        }
      }
    } else {
      float* O = (float*)Out;
#pragma unroll
      for (int st = 0; st < NS; ++st) {
        const int ng = st * 128 + wave * 16 + ln;
#pragma unroll
        for (int rt = 0; rt < 2; ++rt) {
#pragma unroll
          for (int r = 0; r < 4; ++r) {
            const size_t m = rowBase + rt * 16 + quad * 4 + r;
            O[m * N + ng] = acc[st][rt][r];
          }
        }
      }
    }
    __syncthreads();
  }
}

// ---------------------------------------------------------------
// Launch 1: img GEMM (blocks 0..511) + queries GEMM (blocks 512..575,
// grid-strided over 256 tiles) + W_out -> bf16 column-major conversion
// (appendix on the queries-GEMM blocks). The two GEMMs are independent;
// merging removes a launch gap and overlaps the small GEMM with the
// BW-bound big one.
// ---------------------------------------------------------------
__global__ __launch_bounds__(512) void proj_kernel(
    const float* __restrict__ img, const float* __restrict__ queries,
    const float* __restrict__ W_img, const float* __restrict__ b_img,
    const float* __restrict__ W_q, const float* __restrict__ b_q,
    const float* __restrict__ W_out,
    unsigned short* __restrict__ imgp, float* __restrict__ qp,
    unsigned short* __restrict__ wob) {
  __shared__ __align__(16) short lds[32 * 264];
  if (blockIdx.x < 512) {
    gemm_phase<2, 1>(img, W_img, b_img, (void*)imgp, 256, (B_ * I_) / 32,
                     lds, blockIdx.x, 512);
  } else {
    gemm_phase<3, 0>(queries, W_q, b_q, (void*)qp, 384, (B_ * NQ_) / 32,
                     lds, (int)blockIdx.x - 512, 64);
    // --- W_out (256x256 fp32 row-major) -> wob bf16 col-major [col][k] ---
    const int t2 = ((int)blockIdx.x - 512) * 512 + (int)threadIdx.x;  // 0..32767
    const int col = t2 >> 7;          // (2*t2) >> 8
    const int k   = (t2 << 1) & 255;  // even
    const unsigned lo = f2bf(W_out[(size_t)k * 256 + col]);
    const unsigned hi = f2bf(W_out[(size_t)(k + 1) * 256 + col]);
    ((unsigned*)wob)[t2] = lo | (hi << 16);
  }
}

// ---------------------------------------------------------------
// Launch 2: fused softmax + sampling + bilinear gather + output GEMM.
// Block = (batch b, 16 queries, all 8 heads); 256 threads; grid 512.
// Batch-per-XCD: b = blk & 7 (hw round-robin) keeps each XCD's L2 on
// one batch's 11 MB pyramid.
// Per half (8 queries):
//   Phase A (4 iters): item=(q8*8+h)*16+lp -> 16-wide softmax via
//     shfl_xor, fold 4 bilinear corners into 2 contiguous x-PAIRS
//     (head-major imgp: pair = 128 B) -> LDS weights + bases.
//   Phase B (4 iters): item=(q8*8+h)*16+c2; p=c2>>3 picks the pair
//     element, 8 threads cover a 64 B pixel slice with uint2 loads;
//     shfl_xor(8) combines pair halves; result written as 2 bf16 into
//     the 16x264 LDS A-tile (row = query, col = h*32+ch).
// Epilogue: out[16x256] = A @ W_out + b_out via 32 MFMAs; W fragments
// read 16 B-contiguous from wob (L2-hot), so no W register residency.
// ---------------------------------------------------------------
__global__ __launch_bounds__(256) void msda_out_kernel(
    const unsigned int* __restrict__ imgp,  // bf16 pairs, head-major [(b*8+h)*I_][16] uints
    const float* __restrict__ qp, const float* __restrict__ refp,
    const unsigned short* __restrict__ wob, const float* __restrict__ b_out,
    float* __restrict__ out) {
  __shared__ __align__(16) float sw[1024][4];   // 16 KB
  __shared__ __align__(16) int   sib[1024][2];  //  8 KB
  __shared__ __align__(16) short lA[16 * 264];  //  8.25 KB
  const int blk = blockIdx.x;
  const int b   = blk & 7;        // batch-per-XCD
  const int n0  = (blk >> 3) << 4;  // first of 16 queries
  const int tid = threadIdx.x;

  for (int half = 0; half < 2; ++half) {
    // ---------------- phase A ----------------
#pragma unroll
    for (int it = 0; it < 4; ++it) {
      const int item = it * 256 + tid;
      const int lp = item & 15, gh = item >> 4;    // gh = q8*8 + h
      const int q8 = gh >> 3, h = gh & 7;
      const int l = lp >> 2;
      const int ww = 128 >> l;                              // square levels
      const int start = (65536 - (65536 >> (2 * l))) / 3;   // 0,16384,20480,21504
      const float invsh = __uint_as_float((unsigned)(120 + l) << 23);  // 1/ww exactly

      const int n   = n0 + (half << 3) + q8;
      const int bid = (b << 10) | n;
      const float* qb = qp + (size_t)bid * 384 + h * 48 + lp * 3;
      const float ox = qb[0], oy = qb[1], z = qb[2];
      // softmax over the 16 lanes of this (q,h) group
      float m = z;
      m = fmaxf(m, __shfl_xor(m, 1, 16));
      m = fmaxf(m, __shfl_xor(m, 2, 16));
      m = fmaxf(m, __shfl_xor(m, 4, 16));
      m = fmaxf(m, __shfl_xor(m, 8, 16));
      float e = __expf(z - m);
      float s = e;
      s += __shfl_xor(s, 1, 16);
      s += __shfl_xor(s, 2, 16);
      s += __shfl_xor(s, 4, 16);
      s += __shfl_xor(s, 8, 16);
      const float a = e / s;

      const float rx = refp[bid * 2], ry = refp[bid * 2 + 1];
      const float px = (rx + ox * invsh) * (float)ww - 0.5f;
      const float py = (ry + oy * invsh) * (float)ww - 0.5f;
      const float x0f = floorf(px), y0f = floorf(py);
      const float wx = px - x0f, wy = py - y0f;
      const int x0 = (int)x0f, y0 = (int)y0f;

      // fold x-corners onto the contiguous pair (xb, xb+1)
      const int xb = min(max(x0, 0), ww - 2);
      float u0 = 0.f, u1 = 0.f;
      if (x0 >= 0 && x0 < ww)         { if (x0 == xb)     u0 += 1.f - wx; else u1 += 1.f - wx; }
      if (x0 + 1 >= 0 && x0 + 1 < ww) { if (x0 + 1 == xb) u0 += wx;       else u1 += wx; }
      const float wy0 = (y0 >= 0     && y0 < ww)     ? a * (1.f - wy) : 0.f;
      const float wy1 = (y0 + 1 >= 0 && y0 + 1 < ww) ? a * wy         : 0.f;
      const int yc0 = min(max(y0, 0), ww - 1);
      const int yc1 = min(max(y0 + 1, 0), ww - 1);

      const int pb = (b * 8 + h) * I_ + start + xb;
      sw[item][0] = wy0 * u0; sw[item][1] = wy0 * u1;
      sw[item][2] = wy1 * u0; sw[item][3] = wy1 * u1;
      sib[item][0] = (pb + yc0 * ww) * 16;   // uint (bf16-pair) units
      sib[item][1] = (pb + yc1 * ww) * 16;
    }
    __syncthreads();

    // ---------------- phase B ----------------
#pragma unroll
    for (int it = 0; it < 4; ++it) {
      const int item = it * 256 + tid;
      const int c2 = item & 15, gh = item >> 4;
      const int q8 = gh >> 3, h = gh & 7;
      const int p  = c2 >> 3;                    // which pixel of the x-pair
      const int cp = ((c2 & 7) << 1) + (p << 4); // uint offset: pair element + channel pair
      float a0 = 0.f, a1 = 0.f, a2 = 0.f, a3 = 0.f;
#pragma unroll
      for (int lp = 0; lp < 16; ++lp) {
        const float4 w4 = *(const float4*)sw[gh * 16 + lp];   // LDS broadcast
        const int2   ib = *(const int2*)sib[gh * 16 + lp];
        const float w0 = p ? w4.y : w4.x;   // row y0 weight for my pixel
        const float w1 = p ? w4.w : w4.z;   // row y1 weight for my pixel
        const uint2 ua = *(const uint2*)&imgp[ib.x + cp];
        const uint2 ub = *(const uint2*)&imgp[ib.y + cp];
        a0 += w0 * __uint_as_float(ua.x << 16);
        a1 += w0 * __uint_as_float(ua.x & 0xffff0000u);
        a2 += w0 * __uint_as_float(ua.y << 16);
        a3 += w0 * __uint_as_float(ua.y & 0xffff0000u);
        a0 += w1 * __uint_as_float(ub.x << 16);
        a1 += w1 * __uint_as_float(ub.x & 0xffff0000u);
        a2 += w1 * __uint_as_float(ub.y << 16);
        a3 += w1 * __uint_as_float(ub.y & 0xffff0000u);
      }
      // combine the two halves of the x-pair (lanes tid and tid^8: same gh)
      a0 += __shfl_xor(a0, 8);
      a1 += __shfl_xor(a1, 8);
      a2 += __shfl_xor(a2, 8);
      a3 += __shfl_xor(a3, 8);
      const float rx = p ? a2 : a0;
      const float ry = p ? a3 : a1;
      // write 2 bf16 channels into the A-tile: row = query, col = h*32+ch
      const int row = (half << 3) + q8;
      const unsigned pr = (unsigned)f2bf(rx) | ((unsigned)f2bf(ry) << 16);
      *(unsigned*)&lA[row * 264 + h * 32 + ((c2 & 7) << 2) + (p << 1)] = pr;
    }
    __syncthreads();
  }

  // ---------------- MFMA epilogue: out = A @ W_out + b_out ----------------
  const int lane = tid & 63, wv = tid >> 6;   // 4 waves
  const int quad = lane >> 4, ln = lane & 15;
  f32x4 acc[4];
#pragma unroll
  for (int s = 0; s < 4; ++s) {
    const float bb = b_out[wv * 64 + s * 16 + ln];
    acc[s] = f32x4{bb, bb, bb, bb};
  }
#pragma unroll
  for (int ks = 0; ks < 8; ++ks) {
    const s16x8 a = *(const s16x8*)&lA[ln * 264 + ks * 32 + quad * 8];
#pragma unroll
    for (int s = 0; s < 4; ++s) {
      const int ng = wv * 64 + s * 16 + ln;
      const s16x8 wf = *(const s16x8*)&wob[(size_t)ng * 256 + ks * 32 + quad * 8];
      acc[s] = MFMA(a, wf, acc[s]);
    }
  }
#pragma unroll
  for (int s = 0; s < 4; ++s) {
    const int ng = wv * 64 + s * 16 + ln;
#pragma unroll
    for (int r = 0; r < 4; ++r) {
      const int m = quad * 4 + r;   // query row 0..15
      out[(size_t)(b * 1024 + n0 + m) * 256 + ng] = acc[s][r];
    }
  }
}

// ---------------------------------------------------------------
// workspace layout (bytes)
// ---------------------------------------------------------------
#define OFF_IMGP 0ULL                        // 8*8*21760*32*2 = 89,128,960 (bf16, head-major)
#define OFF_QP   89128960ULL                 // 8192*384*4     = 12,582,912
#define OFF_WOB  101711872ULL                // 256*256*2      =    131,072 (bf16 col-major W_out)
#define WS_NEEDED 101842944ULL

extern "C" void kernel_launch(void* const* d_in, const int* in_sizes, int n_in,
                              void* d_out, int out_size, void* d_ws, size_t ws_size,
                              hipStream_t stream) {
  const float* img     = (const float*)d_in[0];
  const float* queries = (const float*)d_in[2];
  const float* refp    = (const float*)d_in[3];
  const float* W_img   = (const float*)d_in[4];
  const float* b_img   = (const float*)d_in[5];
  const float* W_q     = (const float*)d_in[6];
  const float* b_q     = (const float*)d_in[7];
  const float* W_out   = (const float*)d_in[8];
  const float* b_out   = (const float*)d_in[9];

  if (ws_size < WS_NEEDED) return;  // workspace too small -> fail loudly

  char* ws = (char*)d_ws;
  unsigned short* imgp = (unsigned short*)(ws + OFF_IMGP);
  float* qp            = (float*)(ws + OFF_QP);
  unsigned short* wob  = (unsigned short*)(ws + OFF_WOB);

  // launch 1: img proj + queries proj + W_out bf16 conversion
  hipLaunchKernelGGL(proj_kernel, dim3(576), dim3(512), 0, stream,
                     img, queries, W_img, b_img, W_q, b_q, W_out,
                     imgp, qp, wob);
  // launch 2: fused softmax + sampling + gather + output GEMM
  hipLaunchKernelGGL(msda_out_kernel, dim3(512), dim3(256), 0, stream,
                     (const unsigned int*)imgp, qp, refp, wob, b_out,
                     (float*)d_out);
}

// Round 5
// 330.076 us; speedup vs baseline: 1.4650x; 1.0132x over previous
//
#include <hip/hip_runtime.h>
#include <type_traits>
#include <utility>

// ---------------- problem constants ----------------
#define B_    8
#define NQ_   1024
#define I_    21760      // 128*128 + 64*64 + 32*32 + 16*16
#define EMB_  256
#define HID_  256
#define H_    8
#define CH_   32

typedef float  f32x4  __attribute__((ext_vector_type(4)));
typedef __bf16 bf16x8 __attribute__((ext_vector_type(8)));
typedef short  s16x8  __attribute__((ext_vector_type(8)));

// ---- MFMA shim: works whether the builtin wants v8bf16 or v8i16 ----
template <typename V, typename = void>
struct bf16_mfma_native : std::false_type {};
template <typename V>
struct bf16_mfma_native<V, std::void_t<decltype(__builtin_amdgcn_mfma_f32_16x16x32_bf16(
    std::declval<V>(), std::declval<V>(), std::declval<f32x4>(), 0, 0, 0))>>
    : std::true_type {};

template <typename V>
__device__ __forceinline__ f32x4 mfma_dispatch(V a, V b, f32x4 c) {
  if constexpr (bf16_mfma_native<V>::value) {
    return __builtin_amdgcn_mfma_f32_16x16x32_bf16(a, b, c, 0, 0, 0);
  } else {
    return __builtin_amdgcn_mfma_f32_16x16x32_bf16(
        __builtin_bit_cast(s16x8, a), __builtin_bit_cast(s16x8, b), c, 0, 0, 0);
  }
}

__device__ __forceinline__ f32x4 MFMA(s16x8 a, s16x8 b, f32x4 c) {
  return mfma_dispatch(__builtin_bit_cast(bf16x8, a), __builtin_bit_cast(bf16x8, b), c);
}

// float -> bf16 bits, round-to-nearest-even
__device__ __forceinline__ unsigned short f2bf(float f) {
  unsigned u = __float_as_uint(f);
  u += 0x7fffu + ((u >> 16) & 1u);
  return (unsigned short)(u >> 16);
}

// ---------------------------------------------------------------
// GEMM phase, K fixed = 256:  Out[M,N] = A[M,256] @ W[256,N] + bias
// 512 threads = 8 waves. Wave w owns columns {s*128 + w*16 .. +15}.
// W strip in registers. A tile (32 x 256) staged fp32->bf16 into a
// DOUBLE-BUFFERED LDS tile (row stride 264). Per iteration (T14 +
// 2-phase): issue loads(t+1) -> compute(t) from buf[cur] -> epilogue
// stores(t) -> pack(t+1) into buf[cur^1] (waits only the 4 loads) ->
// ONE barrier -> swap. Loads stay in flight across the whole compute.
// OUTM: 0 = fp32 linear [M][N], 1 = bf16 head-major [(b*8+h)][i][32]
// ---------------------------------------------------------------
template <int NS, int OUTM>
__device__ __forceinline__ void gemm_phase(
    const float* __restrict__ A, const float* __restrict__ W,
    const float* __restrict__ bias, void* __restrict__ Out,
    const int N, const int Mtiles, short* __restrict__ lds,
    const int bid0, const int nblk) {
  const int tid  = threadIdx.x;
  const int lane = tid & 63;
  const int wave = tid >> 6;
  const int quad = lane >> 4;
  const int ln   = lane & 15;

  // --- load W fragments (one-time, strided; L2-resident) ---
  s16x8 bfrag[NS][8];
  float bv[NS];
#pragma unroll
  for (int st = 0; st < NS; ++st) {
    const int ng = st * 128 + wave * 16 + ln;
    bv[st] = bias[ng];
#pragma unroll
    for (int ks = 0; ks < 8; ++ks) {
      s16x8 f;
#pragma unroll
      for (int j = 0; j < 8; ++j)
        f[j] = (short)f2bf(W[(ks * 32 + quad * 8 + j) * N + ng]);
      bfrag[st][ks] = f;
    }
  }

  const int sr = tid >> 4;          // staging row 0..31
  const int sc = (tid & 15) * 16;   // staging col (16 floats per thread)

  int t = bid0;
  if (t >= Mtiles) { return; }

  float4 v0, v1, v2, v3;
  // --- prologue: load + pack tile t into buf 0 ---
  {
    const float4* src = (const float4*)(A + ((size_t)t * 32 + sr) * 256 + sc);
    v0 = src[0]; v1 = src[1]; v2 = src[2]; v3 = src[3];
    s16x8 p0, p1;
    p0[0] = (short)f2bf(v0.x); p0[1] = (short)f2bf(v0.y);
    p0[2] = (short)f2bf(v0.z); p0[3] = (short)f2bf(v0.w);
    p0[4] = (short)f2bf(v1.x); p0[5] = (short)f2bf(v1.y);
    p0[6] = (short)f2bf(v1.z); p0[7] = (short)f2bf(v1.w);
    p1[0] = (short)f2bf(v2.x); p1[1] = (short)f2bf(v2.y);
    p1[2] = (short)f2bf(v2.z); p1[3] = (short)f2bf(v2.w);
    p1[4] = (short)f2bf(v3.x); p1[5] = (short)f2bf(v3.y);
    p1[6] = (short)f2bf(v3.z); p1[7] = (short)f2bf(v3.w);
    *(s16x8*)&lds[sr * 264 + sc]     = p0;
    *(s16x8*)&lds[sr * 264 + sc + 8] = p1;
  }
  __syncthreads();

  int cur = 0;
  for (; t < Mtiles; t += nblk) {
    const int tn = t + nblk;
    // --- issue next tile's loads NOW; they fly under the whole compute ---
    if (tn < Mtiles) {
      const float4* src = (const float4*)(A + ((size_t)tn * 32 + sr) * 256 + sc);
      v0 = src[0]; v1 = src[1]; v2 = src[2]; v3 = src[3];
    }

    // --- compute tile t from buf[cur] ---
    short* buf = lds + cur * (32 * 264);
    f32x4 acc[NS][2];
#pragma unroll
    for (int st = 0; st < NS; ++st) {
      acc[st][0] = f32x4{bv[st], bv[st], bv[st], bv[st]};
      acc[st][1] = acc[st][0];
    }
#pragma unroll
    for (int ks = 0; ks < 8; ++ks) {
      s16x8 a0 = *(const s16x8*)&buf[ln * 264 + ks * 32 + quad * 8];
      s16x8 a1 = *(const s16x8*)&buf[(ln + 16) * 264 + ks * 32 + quad * 8];
#pragma unroll
      for (int st = 0; st < NS; ++st) {
        acc[st][0] = MFMA(a0, bfrag[st][ks], acc[st][0]);
        acc[st][1] = MFMA(a1, bfrag[st][ks], acc[st][1]);
      }
    }

    // --- epilogue stores for tile t (issue; drained at the barrier) ---
    const size_t rowBase = (size_t)t * 32;
    if constexpr (OUTM == 1) {
      // bf16 head-major: [(b*8 + h)][i][32]; tiles never cross b (I_%32==0)
      const int tb  = (int)(rowBase / I_);
      const int ir0 = (int)(rowBase - (size_t)tb * I_);
      unsigned short* O = (unsigned short*)Out;
#pragma unroll
      for (int st = 0; st < NS; ++st) {
        const int ng = st * 128 + wave * 16 + ln;
        const int hh = ng >> 5, cc = ng & 31;
        const size_t pl = (size_t)(tb * 8 + hh) * I_;
#pragma unroll
        for (int rt = 0; rt < 2; ++rt) {
#pragma unroll
          for (int r = 0; r < 4; ++r) {
            const size_t i = pl + (size_t)(ir0 + rt * 16 + quad * 4 + r);
            O[i * 32 + cc] = f2bf(acc[st][rt][r]);
          }
        }
      }
    } else {
      float* O = (float*)Out;
#pragma unroll
      for (int st = 0; st < NS; ++st) {
        const int ng = st * 128 + wave * 16 + ln;
#pragma unroll
        for (int rt = 0; rt < 2; ++rt) {
#pragma unroll
          for (int r = 0; r < 4; ++r) {
            const size_t m = rowBase + rt * 16 + quad * 4 + r;
            O[m * N + ng] = acc[st][rt][r];
          }
        }
      }
    }

    // --- pack tile t+1 into buf[cur^1]; waits only the 4 loads ---
    if (tn < Mtiles) {
      short* nbuf = lds + (cur ^ 1) * (32 * 264);
      s16x8 p0, p1;
      p0[0] = (short)f2bf(v0.x); p0[1] = (short)f2bf(v0.y);
      p0[2] = (short)f2bf(v0.z); p0[3] = (short)f2bf(v0.w);
      p0[4] = (short)f2bf(v1.x); p0[5] = (short)f2bf(v1.y);
      p0[6] = (short)f2bf(v1.z); p0[7] = (short)f2bf(v1.w);
      p1[0] = (short)f2bf(v2.x); p1[1] = (short)f2bf(v2.y);
      p1[2] = (short)f2bf(v2.z); p1[3] = (short)f2bf(v2.w);
      p1[4] = (short)f2bf(v3.x); p1[5] = (short)f2bf(v3.y);
      p1[6] = (short)f2bf(v3.z); p1[7] = (short)f2bf(v3.w);
      *(s16x8*)&nbuf[sr * 264 + sc]     = p0;
      *(s16x8*)&nbuf[sr * 264 + sc + 8] = p1;
    }
    __syncthreads();   // single barrier per iteration
    cur ^= 1;
  }
}

// ---------------------------------------------------------------
// Launch 1: grid 512 -> exactly 2 resident blocks per CU (no tail).
// Blocks 0..447: img GEMM (5440 tiles, stride 448).
// Blocks 448..511: queries GEMM (256 tiles, stride 64) + W_out->bf16
// column-major conversion appendix.
// ---------------------------------------------------------------
__global__ __launch_bounds__(512, 4) void proj_kernel(
    const float* __restrict__ img, const float* __restrict__ queries,
    const float* __restrict__ W_img, const float* __restrict__ b_img,
    const float* __restrict__ W_q, const float* __restrict__ b_q,
    const float* __restrict__ W_out,
    unsigned short* __restrict__ imgp, float* __restrict__ qp,
    unsigned short* __restrict__ wob) {
  __shared__ __align__(16) short lds[2 * 32 * 264];   // 33792 B double-buffer
  if (blockIdx.x < 448) {
    gemm_phase<2, 1>(img, W_img, b_img, (void*)imgp, 256, (B_ * I_) / 32,
                     lds, blockIdx.x, 448);
  } else {
    gemm_phase<3, 0>(queries, W_q, b_q, (void*)qp, 384, (B_ * NQ_) / 32,
                     lds, (int)blockIdx.x - 448, 64);
    // --- W_out (256x256 fp32 row-major) -> wob bf16 col-major [col][k] ---
    const int t2 = ((int)blockIdx.x - 448) * 512 + (int)threadIdx.x;  // 0..32767
    const int col = t2 >> 7;          // (2*t2) >> 8
    const int k   = (t2 << 1) & 255;  // even
    const unsigned lo = f2bf(W_out[(size_t)k * 256 + col]);
    const unsigned hi = f2bf(W_out[(size_t)(k + 1) * 256 + col]);
    ((unsigned*)wob)[t2] = lo | (hi << 16);
  }
}

// ---------------------------------------------------------------
// Launch 2: fused softmax + sampling + bilinear gather + output GEMM.
// Block = (batch b, 16 queries, all 8 heads); 256 threads; grid 512.
// Batch-per-XCD: b = blk & 7 (hw round-robin) keeps each XCD's L2 on
// one batch's 11 MB pyramid.
// Per half (8 queries):
//   Phase A (4 iters): item=(q8*8+h)*16+lp -> 16-wide softmax via
//     shfl_xor, fold 4 bilinear corners into 2 contiguous x-PAIRS
//     (head-major imgp: pair = 128 B) -> LDS weights + bases.
//   Phase B (4 iters): item=(q8*8+h)*16+c2; p=c2>>3 picks the pair
//     element, 8 threads cover a 64 B pixel slice with uint2 loads;
//     shfl_xor(8) combines pair halves; result written as 2 bf16 into
//     the 16x264 LDS A-tile (row = query, col = h*32+ch).
// Epilogue: out[16x256] = A @ W_out + b_out via 32 MFMAs; W fragments
// read 16 B-contiguous from wob (L2-hot), so no W register residency.
// ---------------------------------------------------------------
__global__ __launch_bounds__(256) void msda_out_kernel(
    const unsigned int* __restrict__ imgp,  // bf16 pairs, head-major [(b*8+h)*I_][16] uints
    const float* __restrict__ qp, const float* __restrict__ refp,
    const unsigned short* __restrict__ wob, const float* __restrict__ b_out,
    float* __restrict__ out) {
  __shared__ __align__(16) float sw[1024][4];   // 16 KB
  __shared__ __align__(16) int   sib[1024][2];  //  8 KB
  __shared__ __align__(16) short lA[16 * 264];  //  8.25 KB
  const int blk = blockIdx.x;
  const int b   = blk & 7;        // batch-per-XCD
  const int n0  = (blk >> 3) << 4;  // first of 16 queries
  const int tid = threadIdx.x;

  for (int half = 0; half < 2; ++half) {
    // ---------------- phase A ----------------
#pragma unroll
    for (int it = 0; it < 4; ++it) {
      const int item = it * 256 + tid;
      const int lp = item & 15, gh = item >> 4;    // gh = q8*8 + h
      const int q8 = gh >> 3, h = gh & 7;
      const int l = lp >> 2;
      const int ww = 128 >> l;                              // square levels
      const int start = (65536 - (65536 >> (2 * l))) / 3;   // 0,16384,20480,21504
      const float invsh = __uint_as_float((unsigned)(120 + l) << 23);  // 1/ww exactly

      const int n   = n0 + (half << 3) + q8;
      const int bid = (b << 10) | n;
      const float* qb = qp + (size_t)bid * 384 + h * 48 + lp * 3;
      const float ox = qb[0], oy = qb[1], z = qb[2];
      // softmax over the 16 lanes of this (q,h) group
      float m = z;
      m = fmaxf(m, __shfl_xor(m, 1, 16));
      m = fmaxf(m, __shfl_xor(m, 2, 16));
      m = fmaxf(m, __shfl_xor(m, 4, 16));
      m = fmaxf(m, __shfl_xor(m, 8, 16));
      float e = __expf(z - m);
      float s = e;
      s += __shfl_xor(s, 1, 16);
      s += __shfl_xor(s, 2, 16);
      s += __shfl_xor(s, 4, 16);
      s += __shfl_xor(s, 8, 16);
      const float a = e / s;

      const float rx = refp[bid * 2], ry = refp[bid * 2 + 1];
      const float px = (rx + ox * invsh) * (float)ww - 0.5f;
      const float py = (ry + oy * invsh) * (float)ww - 0.5f;
      const float x0f = floorf(px), y0f = floorf(py);
      const float wx = px - x0f, wy = py - y0f;
      const int x0 = (int)x0f, y0 = (int)y0f;

      // fold x-corners onto the contiguous pair (xb, xb+1)
      const int xb = min(max(x0, 0), ww - 2);
      float u0 = 0.f, u1 = 0.f;
      if (x0 >= 0 && x0 < ww)         { if (x0 == xb)     u0 += 1.f - wx; else u1 += 1.f - wx; }
      if (x0 + 1 >= 0 && x0 + 1 < ww) { if (x0 + 1 == xb) u0 += wx;       else u1 += wx; }
      const float wy0 = (y0 >= 0     && y0 < ww)     ? a * (1.f - wy) : 0.f;
      const float wy1 = (y0 + 1 >= 0 && y0 + 1 < ww) ? a * wy         : 0.f;
      const int yc0 = min(max(y0, 0), ww - 1);
      const int yc1 = min(max(y0 + 1, 0), ww - 1);

      const int pb = (b * 8 + h) * I_ + start + xb;
      sw[item][0] = wy0 * u0; sw[item][1] = wy0 * u1;
      sw[item][2] = wy1 * u0; sw[item][3] = wy1 * u1;
      sib[item][0] = (pb + yc0 * ww) * 16;   // uint (bf16-pair) units
      sib[item][1] = (pb + yc1 * ww) * 16;
    }
    __syncthreads();

    // ---------------- phase B ----------------
#pragma unroll
    for (int it = 0; it < 4; ++it) {
      const int item = it * 256 + tid;
      const int c2 = item & 15, gh = item >> 4;
      const int q8 = gh >> 3, h = gh & 7;
      const int p  = c2 >> 3;                    // which pixel of the x-pair
      const int cp = ((c2 & 7) << 1) + (p << 4); // uint offset: pair element + channel pair
      float a0 = 0.f, a1 = 0.f, a2 = 0.f, a3 = 0.f;
#pragma unroll
      for (int lp = 0; lp < 16; ++lp) {
        const float4 w4 = *(const float4*)sw[gh * 16 + lp];   // LDS broadcast
        const int2   ib = *(const int2*)sib[gh * 16 + lp];
        const float w0 = p ? w4.y : w4.x;   // row y0 weight for my pixel
        const float w1 = p ? w4.w : w4.z;   // row y1 weight for my pixel
        const uint2 ua = *(const uint2*)&imgp[ib.x + cp];
        const uint2 ub = *(const uint2*)&imgp[ib.y + cp];
        a0 += w0 * __uint_as_float(ua.x << 16);
        a1 += w0 * __uint_as_float(ua.x & 0xffff0000u);
        a2 += w0 * __uint_as_float(ua.y << 16);
        a3 += w0 * __uint_as_float(ua.y & 0xffff0000u);
        a0 += w1 * __uint_as_float(ub.x << 16);
        a1 += w1 * __uint_as_float(ub.x & 0xffff0000u);
        a2 += w1 * __uint_as_float(ub.y << 16);
        a3 += w1 * __uint_as_float(ub.y & 0xffff0000u);
      }
      // combine the two halves of the x-pair (lanes tid and tid^8: same gh)
      a0 += __shfl_xor(a0, 8);
      a1 += __shfl_xor(a1, 8);
      a2 += __shfl_xor(a2, 8);
      a3 += __shfl_xor(a3, 8);
      const float rx = p ? a2 : a0;
      const float ry = p ? a3 : a1;
      // write 2 bf16 channels into the A-tile: row = query, col = h*32+ch
      const int row = (half << 3) + q8;
      const unsigned pr = (unsigned)f2bf(rx) | ((unsigned)f2bf(ry) << 16);
      *(unsigned*)&lA[row * 264 + h * 32 + ((c2 & 7) << 2) + (p << 1)] = pr;
    }
    __syncthreads();
  }

  // ---------------- MFMA epilogue: out = A @ W_out + b_out ----------------
  const int lane = tid & 63, wv = tid >> 6;   // 4 waves
  const int quad = lane >> 4, ln = lane & 15;
  f32x4 acc[4];
#pragma unroll
  for (int s = 0; s < 4; ++s) {
    const float bb = b_out[wv * 64 + s * 16 + ln];
    acc[s] = f32x4{bb, bb, bb, bb};
  }
#pragma unroll
  for (int ks = 0; ks < 8; ++ks) {
    const s16x8 a = *(const s16x8*)&lA[ln * 264 + ks * 32 + quad * 8];
#pragma unroll
    for (int s = 0; s < 4; ++s) {
      const int ng = wv * 64 + s * 16 + ln;
      const s16x8 wf = *(const s16x8*)&wob[(size_t)ng * 256 + ks * 32 + quad * 8];
      acc[s] = MFMA(a, wf, acc[s]);
    }
  }
#pragma unroll
  for (int s = 0; s < 4; ++s) {
    const int ng = wv * 64 + s * 16 + ln;
#pragma unroll
    for (int r = 0; r < 4; ++r) {
      const int m = quad * 4 + r;   // query row 0..15
      out[(size_t)(b * 1024 + n0 + m) * 256 + ng] = acc[s][r];
    }
  }
}

// ---------------------------------------------------------------
// workspace layout (bytes)
// ---------------------------------------------------------------
#define OFF_IMGP 0ULL                        // 8*8*21760*32*2 = 89,128,960 (bf16, head-major)
#define OFF_QP   89128960ULL                 // 8192*384*4     = 12,582,912
#define OFF_WOB  101711872ULL                // 256*256*2      =    131,072 (bf16 col-major W_out)
#define WS_NEEDED 101842944ULL

extern "C" void kernel_launch(void* const* d_in, const int* in_sizes, int n_in,
                              void* d_out, int out_size, void* d_ws, size_t ws_size,
                              hipStream_t stream) {
  const float* img     = (const float*)d_in[0];
  const float* queries = (const float*)d_in[2];
  const float* refp    = (const float*)d_in[3];
  const float* W_img   = (const float*)d_in[4];
  const float* b_img   = (const float*)d_in[5];
  const float* W_q     = (const float*)d_in[6];
  const float* b_q     = (const float*)d_in[7];
  const float* W_out   = (const float*)d_in[8];
  const float* b_out   = (const float*)d_in[9];

  if (ws_size < WS_NEEDED) return;  // workspace too small -> fail loudly

  char* ws = (char*)d_ws;
  unsigned short* imgp = (unsigned short*)(ws + OFF_IMGP);
  float* qp            = (float*)(ws + OFF_QP);
  unsigned short* wob  = (unsigned short*)(ws + OFF_WOB);

  // launch 1: img proj + queries proj + W_out bf16 conversion
  hipLaunchKernelGGL(proj_kernel, dim3(512), dim3(512), 0, stream,
                     img, queries, W_img, b_img, W_q, b_q, W_out,
                     imgp, qp, wob);
  // launch 2: fused softmax + sampling + gather + output GEMM
  hipLaunchKernelGGL(msda_out_kernel, dim3(512), dim3(256), 0, stream,
                     (const unsigned int*)imgp, qp, refp, wob, b_out,
                     (float*)d_out);
}

// Round 6
// 323.365 us; speedup vs baseline: 1.4954x; 1.0208x over previous
//
#include <hip/hip_runtime.h>
#include <type_traits>
#include <utility>

// ---------------- problem constants ----------------
#define B_    8
#define NQ_   1024
#define I_    21760      // 128*128 + 64*64 + 32*32 + 16*16
#define EMB_  256
#define HID_  256
#define H_    8
#define CH_   32

typedef float  f32x4  __attribute__((ext_vector_type(4)));
typedef __bf16 bf16x8 __attribute__((ext_vector_type(8)));
typedef short  s16x8  __attribute__((ext_vector_type(8)));

// ---- MFMA shim: works whether the builtin wants v8bf16 or v8i16 ----
template <typename V, typename = void>
struct bf16_mfma_native : std::false_type {};
template <typename V>
struct bf16_mfma_native<V, std::void_t<decltype(__builtin_amdgcn_mfma_f32_16x16x32_bf16(
    std::declval<V>(), std::declval<V>(), std::declval<f32x4>(), 0, 0, 0))>>
    : std::true_type {};

template <typename V>
__device__ __forceinline__ f32x4 mfma_dispatch(V a, V b, f32x4 c) {
  if constexpr (bf16_mfma_native<V>::value) {
    return __builtin_amdgcn_mfma_f32_16x16x32_bf16(a, b, c, 0, 0, 0);
  } else {
    return __builtin_amdgcn_mfma_f32_16x16x32_bf16(
        __builtin_bit_cast(s16x8, a), __builtin_bit_cast(s16x8, b), c, 0, 0, 0);
  }
}

__device__ __forceinline__ f32x4 MFMA(s16x8 a, s16x8 b, f32x4 c) {
  return mfma_dispatch(__builtin_bit_cast(bf16x8, a), __builtin_bit_cast(bf16x8, b), c);
}

// float -> bf16 bits, round-to-nearest-even
__device__ __forceinline__ unsigned short f2bf(float f) {
  unsigned u = __float_as_uint(f);
  u += 0x7fffu + ((u >> 16) & 1u);
  return (unsigned short)(u >> 16);
}

// ---------------------------------------------------------------
// convert_w: W (fp32 row-major [k][col]) -> bf16 col-major [col][k]
// (fragment-ready: 16 B per MFMA B-frag contiguous in k).
// 114688 uints total: wib 32768, wqb 49152, wob 32768.
// ---------------------------------------------------------------
__global__ __launch_bounds__(512) void convert_w(
    const float* __restrict__ Wi, const float* __restrict__ Wq,
    const float* __restrict__ Wo, unsigned* __restrict__ wib,
    unsigned* __restrict__ wqb, unsigned* __restrict__ wob) {
  const int g = blockIdx.x * 512 + threadIdx.x;   // 0..114687
  const float* S;
  unsigned* D;
  int N, t;
  if (g < 32768)      { S = Wi; D = wib; N = 256; t = g; }
  else if (g < 81920) { S = Wq; D = wqb; N = 384; t = g - 32768; }
  else                { S = Wo; D = wob; N = 256; t = g - 81920; }
  const int col = t >> 7, k = (t & 127) << 1;
  const unsigned lo = f2bf(S[(size_t)k * N + col]);
  const unsigned hi = f2bf(S[(size_t)(k + 1) * N + col]);
  D[t] = lo | (hi << 16);
}

// ---------------------------------------------------------------
// GEMM phase, K fixed = 256:  Out[M,N] = A[M,256] @ W[256,N] + bias
// 512 threads = 8 waves. Wave w owns columns {s*128 + w*16 .. +15}.
// W fragments are NOT held in registers (that spilled: NS*8*4 = 64-96
// VGPRs); they are STREAMED per k-step from the bf16 col-major table
// Wb (L2-resident, 16 B contiguous per frag) — same pattern as the
// msda epilogue. A tile (32 x 256) staged fp32->bf16 into a double-
// buffered LDS tile (row stride 264); issue loads(t+1) -> compute(t)
// -> stores(t) -> pack(t+1) -> ONE barrier.
// OUTM: 0 = fp32 linear [M][N], 1 = bf16 head-major [(b*8+h)][i][32]
// ---------------------------------------------------------------
template <int NS, int OUTM>
__device__ __forceinline__ void gemm_phase(
    const float* __restrict__ A, const unsigned short* __restrict__ Wb,
    const float* __restrict__ bias, void* __restrict__ Out,
    const int N, const int Mtiles, short* __restrict__ lds,
    const int bid0, const int nblk) {
  const int tid  = threadIdx.x;
  const int lane = tid & 63;
  const int wave = tid >> 6;
  const int quad = lane >> 4;
  const int ln   = lane & 15;

  float bv[NS];
#pragma unroll
  for (int st = 0; st < NS; ++st) bv[st] = bias[st * 128 + wave * 16 + ln];

  // per-thread W-frag base (bytes advance with ks inside the loop)
  const unsigned short* wbase = Wb + (size_t)(wave * 16 + ln) * 256 + quad * 8;

  const int sr = tid >> 4;          // staging row 0..31
  const int sc = (tid & 15) * 16;   // staging col (16 floats per thread)

  int t = bid0;
  if (t >= Mtiles) { return; }

  float4 v0, v1, v2, v3;
  // --- prologue: load + pack tile t into buf 0 ---
  {
    const float4* src = (const float4*)(A + ((size_t)t * 32 + sr) * 256 + sc);
    v0 = src[0]; v1 = src[1]; v2 = src[2]; v3 = src[3];
    s16x8 p0, p1;
    p0[0] = (short)f2bf(v0.x); p0[1] = (short)f2bf(v0.y);
    p0[2] = (short)f2bf(v0.z); p0[3] = (short)f2bf(v0.w);
    p0[4] = (short)f2bf(v1.x); p0[5] = (short)f2bf(v1.y);
    p0[6] = (short)f2bf(v1.z); p0[7] = (short)f2bf(v1.w);
    p1[0] = (short)f2bf(v2.x); p1[1] = (short)f2bf(v2.y);
    p1[2] = (short)f2bf(v2.z); p1[3] = (short)f2bf(v2.w);
    p1[4] = (short)f2bf(v3.x); p1[5] = (short)f2bf(v3.y);
    p1[6] = (short)f2bf(v3.z); p1[7] = (short)f2bf(v3.w);
    *(s16x8*)&lds[sr * 264 + sc]     = p0;
    *(s16x8*)&lds[sr * 264 + sc + 8] = p1;
  }
  __syncthreads();

  int cur = 0;
  for (; t < Mtiles; t += nblk) {
    const int tn = t + nblk;
    // --- issue next tile's loads NOW; they fly under the whole compute ---
    if (tn < Mtiles) {
      const float4* src = (const float4*)(A + ((size_t)tn * 32 + sr) * 256 + sc);
      v0 = src[0]; v1 = src[1]; v2 = src[2]; v3 = src[3];
    }

    // --- compute tile t from buf[cur]; W frags streamed from L2 ---
    short* buf = lds + cur * (32 * 264);
    f32x4 acc[NS][2];
#pragma unroll
    for (int st = 0; st < NS; ++st) {
      acc[st][0] = f32x4{bv[st], bv[st], bv[st], bv[st]};
      acc[st][1] = acc[st][0];
    }
#pragma unroll
    for (int ks = 0; ks < 8; ++ks) {
      s16x8 a0 = *(const s16x8*)&buf[ln * 264 + ks * 32 + quad * 8];
      s16x8 a1 = *(const s16x8*)&buf[(ln + 16) * 264 + ks * 32 + quad * 8];
#pragma unroll
      for (int st = 0; st < NS; ++st) {
        const s16x8 wf = *(const s16x8*)&wbase[(size_t)st * 128 * 256 + ks * 32];
        acc[st][0] = MFMA(a0, wf, acc[st][0]);
        acc[st][1] = MFMA(a1, wf, acc[st][1]);
      }
    }

    // --- epilogue stores for tile t (issue; drained at the barrier) ---
    const size_t rowBase = (size_t)t * 32;
    if constexpr (OUTM == 1) {
      // bf16 head-major: [(b*8 + h)][i][32]; tiles never cross b (I_%32==0)
      const int tb  = (int)(rowBase / I_);
      const int ir0 = (int)(rowBase - (size_t)tb * I_);
      unsigned short* O = (unsigned short*)Out;
#pragma unroll
      for (int st = 0; st < NS; ++st) {
        const int ng = st * 128 + wave * 16 + ln;
        const int hh = ng >> 5, cc = ng & 31;
        const size_t pl = (size_t)(tb * 8 + hh) * I_;
#pragma unroll
        for (int rt = 0; rt < 2; ++rt) {
#pragma unroll
          for (int r = 0; r < 4; ++r) {
            const size_t i = pl + (size_t)(ir0 + rt * 16 + quad * 4 + r);
            O[i * 32 + cc] = f2bf(acc[st][rt][r]);
          }
        }
      }
    } else {
      float* O = (float*)Out;
#pragma unroll
      for (int st = 0; st < NS; ++st) {
        const int ng = st * 128 + wave * 16 + ln;
#pragma unroll
        for (int rt = 0; rt < 2; ++rt) {
#pragma unroll
          for (int r = 0; r < 4; ++r) {
            const size_t m = rowBase + rt * 16 + quad * 4 + r;
            O[m * N + ng] = acc[st][rt][r];
          }
        }
      }
    }

    // --- pack tile t+1 into buf[cur^1]; waits only the 4 loads ---
    if (tn < Mtiles) {
      short* nbuf = lds + (cur ^ 1) * (32 * 264);
      s16x8 p0, p1;
      p0[0] = (short)f2bf(v0.x); p0[1] = (short)f2bf(v0.y);
      p0[2] = (short)f2bf(v0.z); p0[3] = (short)f2bf(v0.w);
      p0[4] = (short)f2bf(v1.x); p0[5] = (short)f2bf(v1.y);
      p0[6] = (short)f2bf(v1.z); p0[7] = (short)f2bf(v1.w);
      p1[0] = (short)f2bf(v2.x); p1[1] = (short)f2bf(v2.y);
      p1[2] = (short)f2bf(v2.z); p1[3] = (short)f2bf(v2.w);
      p1[4] = (short)f2bf(v3.x); p1[5] = (short)f2bf(v3.y);
      p1[6] = (short)f2bf(v3.z); p1[7] = (short)f2bf(v3.w);
      *(s16x8*)&nbuf[sr * 264 + sc]     = p0;
      *(s16x8*)&nbuf[sr * 264 + sc + 8] = p1;
    }
    __syncthreads();   // single barrier per iteration
    cur ^= 1;
  }
}

// ---------------------------------------------------------------
// Launch 2: grid 768 -> 3 resident blocks per CU.
// Blocks 0..703: img GEMM (5440 tiles, stride 704).
// Blocks 704..767: queries GEMM (256 tiles, stride 64).
// ---------------------------------------------------------------
__global__ __launch_bounds__(512) void proj_kernel(
    const float* __restrict__ img, const float* __restrict__ queries,
    const unsigned short* __restrict__ wib, const float* __restrict__ b_img,
    const unsigned short* __restrict__ wqb, const float* __restrict__ b_q,
    unsigned short* __restrict__ imgp, float* __restrict__ qp) {
  __shared__ __align__(16) short lds[2 * 32 * 264];   // 33792 B double-buffer
  if (blockIdx.x < 704) {
    gemm_phase<2, 1>(img, wib, b_img, (void*)imgp, 256, (B_ * I_) / 32,
                     lds, blockIdx.x, 704);
  } else {
    gemm_phase<3, 0>(queries, wqb, b_q, (void*)qp, 384, (B_ * NQ_) / 32,
                     lds, (int)blockIdx.x - 704, 64);
  }
}

// ---------------------------------------------------------------
// Launch 3: fused softmax + sampling + bilinear gather + output GEMM.
// Block = (batch b, 16 queries, all 8 heads); 256 threads; grid 512.
// Batch-per-XCD: b = blk & 7 (hw round-robin) keeps each XCD's L2 on
// one batch's 11 MB pyramid.
// Per half (8 queries):
//   Phase A (4 iters): item=(q8*8+h)*16+lp -> 16-wide softmax via
//     shfl_xor, fold 4 bilinear corners into 2 contiguous x-PAIRS
//     (head-major imgp: pair = 128 B) -> LDS weights + bases.
//   Phase B (4 iters): item=(q8*8+h)*16+c2; p=c2>>3 picks the pair
//     element, 8 threads cover a 64 B pixel slice with uint2 loads;
//     shfl_xor(8) combines pair halves; result written as 2 bf16 into
//     the 16x264 LDS A-tile (row = query, col = h*32+ch).
// Epilogue: out[16x256] = A @ W_out + b_out via 32 MFMAs; W fragments
// read 16 B-contiguous from wob (L2-hot), so no W register residency.
// ---------------------------------------------------------------
__global__ __launch_bounds__(256) void msda_out_kernel(
    const unsigned int* __restrict__ imgp,  // bf16 pairs, head-major [(b*8+h)*I_][16] uints
    const float* __restrict__ qp, const float* __restrict__ refp,
    const unsigned short* __restrict__ wob, const float* __restrict__ b_out,
    float* __restrict__ out) {
  __shared__ __align__(16) float sw[1024][4];   // 16 KB
  __shared__ __align__(16) int   sib[1024][2];  //  8 KB
  __shared__ __align__(16) short lA[16 * 264];  //  8.25 KB
  const int blk = blockIdx.x;
  const int b   = blk & 7;        // batch-per-XCD
  const int n0  = (blk >> 3) << 4;  // first of 16 queries
  const int tid = threadIdx.x;

  for (int half = 0; half < 2; ++half) {
    // ---------------- phase A ----------------
#pragma unroll
    for (int it = 0; it < 4; ++it) {
      const int item = it * 256 + tid;
      const int lp = item & 15, gh = item >> 4;    // gh = q8*8 + h
      const int q8 = gh >> 3, h = gh & 7;
      const int l = lp >> 2;
      const int ww = 128 >> l;                              // square levels
      const int start = (65536 - (65536 >> (2 * l))) / 3;   // 0,16384,20480,21504
      const float invsh = __uint_as_float((unsigned)(120 + l) << 23);  // 1/ww exactly

      const int n   = n0 + (half << 3) + q8;
      const int bid = (b << 10) | n;
      const float* qb = qp + (size_t)bid * 384 + h * 48 + lp * 3;
      const float ox = qb[0], oy = qb[1], z = qb[2];
      // softmax over the 16 lanes of this (q,h) group
      float m = z;
      m = fmaxf(m, __shfl_xor(m, 1, 16));
      m = fmaxf(m, __shfl_xor(m, 2, 16));
      m = fmaxf(m, __shfl_xor(m, 4, 16));
      m = fmaxf(m, __shfl_xor(m, 8, 16));
      float e = __expf(z - m);
      float s = e;
      s += __shfl_xor(s, 1, 16);
      s += __shfl_xor(s, 2, 16);
      s += __shfl_xor(s, 4, 16);
      s += __shfl_xor(s, 8, 16);
      const float a = e / s;

      const float rx = refp[bid * 2], ry = refp[bid * 2 + 1];
      const float px = (rx + ox * invsh) * (float)ww - 0.5f;
      const float py = (ry + oy * invsh) * (float)ww - 0.5f;
      const float x0f = floorf(px), y0f = floorf(py);
      const float wx = px - x0f, wy = py - y0f;
      const int x0 = (int)x0f, y0 = (int)y0f;

      // fold x-corners onto the contiguous pair (xb, xb+1)
      const int xb = min(max(x0, 0), ww - 2);
      float u0 = 0.f, u1 = 0.f;
      if (x0 >= 0 && x0 < ww)         { if (x0 == xb)     u0 += 1.f - wx; else u1 += 1.f - wx; }
      if (x0 + 1 >= 0 && x0 + 1 < ww) { if (x0 + 1 == xb) u0 += wx;       else u1 += wx; }
      const float wy0 = (y0 >= 0     && y0 < ww)     ? a * (1.f - wy) : 0.f;
      const float wy1 = (y0 + 1 >= 0 && y0 + 1 < ww) ? a * wy         : 0.f;
      const int yc0 = min(max(y0, 0), ww - 1);
      const int yc1 = min(max(y0 + 1, 0), ww - 1);

      const int pb = (b * 8 + h) * I_ + start + xb;
      sw[item][0] = wy0 * u0; sw[item][1] = wy0 * u1;
      sw[item][2] = wy1 * u0; sw[item][3] = wy1 * u1;
      sib[item][0] = (pb + yc0 * ww) * 16;   // uint (bf16-pair) units
      sib[item][1] = (pb + yc1 * ww) * 16;
    }
    __syncthreads();

    // ---------------- phase B ----------------
#pragma unroll
    for (int it = 0; it < 4; ++it) {
      const int item = it * 256 + tid;
      const int c2 = item & 15, gh = item >> 4;
      const int q8 = gh >> 3, h = gh & 7;
      const int p  = c2 >> 3;                    // which pixel of the x-pair
      const int cp = ((c2 & 7) << 1) + (p << 4); // uint offset: pair element + channel pair
      float a0 = 0.f, a1 = 0.f, a2 = 0.f, a3 = 0.f;
#pragma unroll
      for (int lp = 0; lp < 16; ++lp) {
        const float4 w4 = *(const float4*)sw[gh * 16 + lp];   // LDS broadcast
        const int2   ib = *(const int2*)sib[gh * 16 + lp];
        const float w0 = p ? w4.y : w4.x;   // row y0 weight for my pixel
        const float w1 = p ? w4.w : w4.z;   // row y1 weight for my pixel
        const uint2 ua = *(const uint2*)&imgp[ib.x + cp];
        const uint2 ub = *(const uint2*)&imgp[ib.y + cp];
        a0 += w0 * __uint_as_float(ua.x << 16);
        a1 += w0 * __uint_as_float(ua.x & 0xffff0000u);
        a2 += w0 * __uint_as_float(ua.y << 16);
        a3 += w0 * __uint_as_float(ua.y & 0xffff0000u);
        a0 += w1 * __uint_as_float(ub.x << 16);
        a1 += w1 * __uint_as_float(ub.x & 0xffff0000u);
        a2 += w1 * __uint_as_float(ub.y << 16);
        a3 += w1 * __uint_as_float(ub.y & 0xffff0000u);
      }
      // combine the two halves of the x-pair (lanes tid and tid^8: same gh)
      a0 += __shfl_xor(a0, 8);
      a1 += __shfl_xor(a1, 8);
      a2 += __shfl_xor(a2, 8);
      a3 += __shfl_xor(a3, 8);
      const float rx = p ? a2 : a0;
      const float ry = p ? a3 : a1;
      // write 2 bf16 channels into the A-tile: row = query, col = h*32+ch
      const int row = (half << 3) + q8;
      const unsigned pr = (unsigned)f2bf(rx) | ((unsigned)f2bf(ry) << 16);
      *(unsigned*)&lA[row * 264 + h * 32 + ((c2 & 7) << 2) + (p << 1)] = pr;
    }
    __syncthreads();
  }

  // ---------------- MFMA epilogue: out = A @ W_out + b_out ----------------
  const int lane = tid & 63, wv = tid >> 6;   // 4 waves
  const int quad = lane >> 4, ln = lane & 15;
  f32x4 acc[4];
#pragma unroll
  for (int s = 0; s < 4; ++s) {
    const float bb = b_out[wv * 64 + s * 16 + ln];
    acc[s] = f32x4{bb, bb, bb, bb};
  }
#pragma unroll
  for (int ks = 0; ks < 8; ++ks) {
    const s16x8 a = *(const s16x8*)&lA[ln * 264 + ks * 32 + quad * 8];
#pragma unroll
    for (int s = 0; s < 4; ++s) {
      const int ng = wv * 64 + s * 16 + ln;
      const s16x8 wf = *(const s16x8*)&wob[(size_t)ng * 256 + ks * 32 + quad * 8];
      acc[s] = MFMA(a, wf, acc[s]);
    }
  }
#pragma unroll
  for (int s = 0; s < 4; ++s) {
    const int ng = wv * 64 + s * 16 + ln;
#pragma unroll
    for (int r = 0; r < 4; ++r) {
      const int m = quad * 4 + r;   // query row 0..15
      out[(size_t)(b * 1024 + n0 + m) * 256 + ng] = acc[s][r];
    }
  }
}

// ---------------------------------------------------------------
// workspace layout (bytes)
// ---------------------------------------------------------------
#define OFF_IMGP 0ULL                        // 8*8*21760*32*2 = 89,128,960 (bf16, head-major)
#define OFF_QP   89128960ULL                 // 8192*384*4     = 12,582,912
#define OFF_WIB  101711872ULL                // 256*256*2      =    131,072 (bf16 col-major W_img)
#define OFF_WQB  101842944ULL                // 384*256*2      =    196,608 (bf16 col-major W_q)
#define OFF_WOB  102039552ULL                // 256*256*2      =    131,072 (bf16 col-major W_out)
#define WS_NEEDED 102170624ULL

extern "C" void kernel_launch(void* const* d_in, const int* in_sizes, int n_in,
                              void* d_out, int out_size, void* d_ws, size_t ws_size,
                              hipStream_t stream) {
  const float* img     = (const float*)d_in[0];
  const float* queries = (const float*)d_in[2];
  const float* refp    = (const float*)d_in[3];
  const float* W_img   = (const float*)d_in[4];
  const float* b_img   = (const float*)d_in[5];
  const float* W_q     = (const float*)d_in[6];
  const float* b_q     = (const float*)d_in[7];
  const float* W_out   = (const float*)d_in[8];
  const float* b_out   = (const float*)d_in[9];

  if (ws_size < WS_NEEDED) return;  // workspace too small -> fail loudly

  char* ws = (char*)d_ws;
  unsigned short* imgp = (unsigned short*)(ws + OFF_IMGP);
  float* qp            = (float*)(ws + OFF_QP);
  unsigned short* wib  = (unsigned short*)(ws + OFF_WIB);
  unsigned short* wqb  = (unsigned short*)(ws + OFF_WQB);
  unsigned short* wob  = (unsigned short*)(ws + OFF_WOB);

  // launch 1: W matrices -> bf16 col-major fragment tables (0.9 MB)
  hipLaunchKernelGGL(convert_w, dim3(224), dim3(512), 0, stream,
                     W_img, W_q, W_out,
                     (unsigned*)wib, (unsigned*)wqb, (unsigned*)wob);
  // launch 2: img proj + queries proj (W streamed from L2, no spills)
  hipLaunchKernelGGL(proj_kernel, dim3(768), dim3(512), 0, stream,
                     img, queries, wib, b_img, wqb, b_q, imgp, qp);
  // launch 3: fused softmax + sampling + gather + output GEMM
  hipLaunchKernelGGL(msda_out_kernel, dim3(512), dim3(256), 0, stream,
                     (const unsigned int*)imgp, qp, refp, wob, b_out,
                     (float*)d_out);
}